// Round 6
// baseline (515.728 us; speedup 1.0000x reference)
//
#include <hip/hip_runtime.h>
#include <math.h>

#define NN 100000
#define NE 1600000
#define DI 256
#define DH 64
#define DO 47
#define NB ((NN + 255) / 256)       // 391 scan blocks
#define NRANGE 4                    // dst ranges for locality-phased fill
#define RSZ ((NN + NRANGE - 1) / NRANGE)      // 25000 nodes per range
#define EPB 2048                    // edges per fill block
#define CPB ((NE + EPB - 1) / EPB)  // 782 chunks per range
#define HGRID (NN / 4)              // blocks per feature-half pass

typedef float f8 __attribute__((ext_vector_type(8)));

// ---------------- degree (int atomics, deterministic) ----------------
__global__ __launch_bounds__(256) void k_degree(const int* __restrict__ dst,
                                                int* __restrict__ deg) {
    int e = blockIdx.x * 256 + threadIdx.x;
    if (e < NE) atomicAdd(&deg[dst[e]], 1);
}

__global__ __launch_bounds__(256) void k_dinv(const int* __restrict__ deg,
                                              float* __restrict__ dinv) {
    int i = blockIdx.x * 256 + threadIdx.x;
    if (i < NN) dinv[i] = rsqrtf((float)(deg[i] + 1));
}

// ---------------- scan pass 1: per-block sums of deg ----------------
__global__ __launch_bounds__(256) void k_part(const int* __restrict__ deg,
                                              int* __restrict__ part) {
    int i = blockIdx.x * 256 + threadIdx.x;
    int v = (i < NN) ? deg[i] : 0;
    for (int off = 32; off; off >>= 1) v += __shfl_xor(v, off);
    __shared__ int s[4];
    if ((threadIdx.x & 63) == 0) s[threadIdx.x >> 6] = v;
    __syncthreads();
    if (threadIdx.x == 0) part[blockIdx.x] = s[0] + s[1] + s[2] + s[3];
}

// ---------------- scan pass 2: exclusive scan of partials (NB<=512) ----------------
__global__ __launch_bounds__(512) void k_scanpart(int* __restrict__ part) {
    int t = threadIdx.x, lane = t & 63, wv = t >> 6;
    int v0 = (t < NB) ? part[t] : 0;
    int v = v0;
    for (int off = 1; off < 64; off <<= 1) {
        int u = __shfl_up(v, off);
        if (lane >= off) v += u;
    }
    __shared__ int ws[8];
    if (lane == 63) ws[wv] = v;
    __syncthreads();
    if (t == 0) {
        int run = 0;
        for (int w = 0; w < 8; ++w) { int tmp = ws[w]; ws[w] = run; run += tmp; }
    }
    __syncthreads();
    v += ws[wv];
    if (t < NB) part[t] = v - v0;   // exclusive
}

// ---------------- scan pass 3: per-element exclusive prefix -> rowptr, cursor ----------------
__global__ __launch_bounds__(256) void k_scan3(const int* __restrict__ deg,
                                               const int* __restrict__ part,
                                               int* __restrict__ rowptr,
                                               int* __restrict__ cursor) {
    int i = blockIdx.x * 256 + threadIdx.x;
    int lane = threadIdx.x & 63, wv = threadIdx.x >> 6;
    int v0 = (i < NN) ? deg[i] : 0;
    int v = v0;
    for (int off = 1; off < 64; off <<= 1) {
        int u = __shfl_up(v, off);
        if (lane >= off) v += u;
    }
    __shared__ int ws[4], wo[4];
    if (lane == 63) ws[wv] = v;
    __syncthreads();
    if (threadIdx.x == 0) {
        int run = 0;
        for (int w = 0; w < 4; ++w) { int tmp = ws[w]; wo[w] = run; run += tmp; }
    }
    __syncthreads();
    int excl = part[blockIdx.x] + wo[wv] + v - v0;
    if (i < NN) { rowptr[i] = excl; cursor[i] = excl; }
}

// ---------------- range-phased bucket-fill ----------------
__global__ __launch_bounds__(256) void k_fillr(const int* __restrict__ src,
                                               const int* __restrict__ dst,
                                               int* __restrict__ cursor,
                                               int* __restrict__ csr_src) {
    int r = blockIdx.x / CPB;
    int chunk = blockIdx.x % CPB;
    int lo = r * RSZ, hi = lo + RSZ;   // [lo, hi)
    int base = chunk * EPB + threadIdx.x;
    #pragma unroll
    for (int i = 0; i < EPB / 256; ++i) {
        int e = base + i * 256;
        if (e < NE) {
            int d = dst[e];
            if (d >= lo && d < hi) {
                int p = atomicAdd(&cursor[d], 1);
                csr_src[p] = src[e];
            }
        }
    }
}

// ---------------- h1s = dinv * (x @ W1)  (N x 256 x 64), fp32 ----------------
__global__ __launch_bounds__(512) void k_gemm1(const float* __restrict__ x,
                                               const float* __restrict__ W1,
                                               const float* __restrict__ dinv,
                                               float* __restrict__ h1s) {
    __shared__ float xs[2][64 * 17];
    const int t = threadIdx.x;
    const int lane = t & 63;
    const int wvu = __builtin_amdgcn_readfirstlane(t >> 6);  // uniform wave id
    const int r0 = blockIdx.x * 64;
    const int sr = t >> 3;
    const int sk = (t & 7) * 2;
    const long xrow = (long)min(r0 + sr, NN - 1) * DI;
    const int row = r0 + lane;

    float acc[8] = {0.f, 0.f, 0.f, 0.f, 0.f, 0.f, 0.f, 0.f};

    {   // stage chunk 0
        float2 v = *(const float2*)(x + xrow + sk);
        xs[0][sr * 17 + sk] = v.x;
        xs[0][sr * 17 + sk + 1] = v.y;
    }
    __syncthreads();
    for (int c = 0; c < 16; ++c) {
        const int buf = c & 1;
        if (c + 1 < 16) {
            float2 v = *(const float2*)(x + xrow + (c + 1) * 16 + sk);
            xs[buf ^ 1][sr * 17 + sk] = v.x;
            xs[buf ^ 1][sr * 17 + sk + 1] = v.y;
        }
        const f8* wp = (const f8*)(W1) + (size_t)(c * 16) * (DH / 8) + wvu;
        #pragma unroll
        for (int k = 0; k < 16; ++k) {
            float xv = xs[buf][lane * 17 + k];
            f8 w8 = wp[(size_t)k * (DH / 8)];
            #pragma unroll
            for (int j = 0; j < 8; ++j) acc[j] += w8[j] * xv;
        }
        __syncthreads();
    }
    if (row < NN) {
        float di = dinv[row];
        float4 o0 = {di * acc[0], di * acc[1], di * acc[2], di * acc[3]};
        float4 o1 = {di * acc[4], di * acc[5], di * acc[6], di * acc[7]};
        float4* hp = (float4*)(h1s + (long)row * DH + wvu * 8);
        hp[0] = o0;
        hp[1] = o1;
    }
}

// ---------------- layer1 gather, feature-split (2 passes of 32 cols) ----------------
// Wave = one dst row; 64 lanes = 2 edges x 32 features (one 128B line per edge).
// Pass p covers cols [32p, 32p+32). Writes h2 = relu(di*(sum + self) + b1).
__global__ __launch_bounds__(256) void k_agg1h(const int* __restrict__ rowptr,
                                               const int* __restrict__ deg,
                                               const int* __restrict__ csr_src,
                                               const float* __restrict__ dinv,
                                               const float* __restrict__ h1s,
                                               const float* __restrict__ b1,
                                               float* __restrict__ h2) {
    int half = (blockIdx.x >= HGRID) ? 1 : 0;
    int blk = blockIdx.x - half * HGRID;
    int wv = threadIdx.x >> 6, lane = threadIdx.x & 63;
    int row = blk * 4 + wv;
    int f = (lane & 31) + half * 32;
    int eh = lane >> 5;
    int beg = rowptr[row], cnt = deg[row];
    float acc = 0.f;
    int j = 0;
    for (; j + 7 < cnt; j += 8) {
        int s0 = csr_src[beg + j + 0 + eh], s1 = csr_src[beg + j + 2 + eh];
        int s2 = csr_src[beg + j + 4 + eh], s3 = csr_src[beg + j + 6 + eh];
        float v0 = h1s[(long)s0 * DH + f], v1 = h1s[(long)s1 * DH + f];
        float v2 = h1s[(long)s2 * DH + f], v3 = h1s[(long)s3 * DH + f];
        acc += (v0 + v1) + (v2 + v3);
    }
    for (; j < cnt; j += 2) {
        int jj = j + eh;
        if (jj < cnt) {
            int s = csr_src[beg + jj];
            acc += h1s[(long)s * DH + f];
        }
    }
    acc += __shfl_xor(acc, 32);
    if (lane < 32) {
        float di = dinv[row];
        float v = di * (acc + h1s[(long)row * DH + f]) + b1[f];
        h2[(long)row * DH + f] = fmaxf(v, 0.f);
    }
}

// ---------------- GEMM2: h3s = dinv * (h2 @ W2), row stride 64 (padded) ----------------
__global__ __launch_bounds__(256) void k_gemm2(const float* __restrict__ h2,
                                               const float* __restrict__ W2,
                                               const float* __restrict__ dinv,
                                               float* __restrict__ h3s) {
    __shared__ float w2[DH * DO];   // 12 KB
    __shared__ float sh[4][DH];
    for (int i = threadIdx.x; i < DH * DO; i += 256) w2[i] = W2[i];
    int wv = threadIdx.x >> 6, lane = threadIdx.x & 63;
    int row = blockIdx.x * 4 + wv;
    sh[wv][lane] = h2[(long)row * DH + lane];
    __syncthreads();
    if (lane < DO) {
        float o = 0.f;
        #pragma unroll 8
        for (int k = 0; k < DH; ++k)
            o += sh[wv][k] * w2[k * DO + lane];
        h3s[(long)row * DH + lane] = dinv[row] * o;
    }
}

// ---------------- layer2 gather, feature-split (2 passes) ----------------
// Pass 0: cols [0,32) (full line A). Pass 1: cols [32,47) (line B).
// Writes xo = di*(sum + self) + b2 directly.
__global__ __launch_bounds__(256) void k_agg2h(const int* __restrict__ rowptr,
                                               const int* __restrict__ deg,
                                               const int* __restrict__ csr_src,
                                               const float* __restrict__ dinv,
                                               const float* __restrict__ h3s,
                                               const float* __restrict__ b2,
                                               float* __restrict__ xo) {
    int half = (blockIdx.x >= HGRID) ? 1 : 0;
    int blk = blockIdx.x - half * HGRID;
    int wv = threadIdx.x >> 6, lane = threadIdx.x & 63;
    int row = blk * 4 + wv;
    int f = (lane & 31) + half * 32;
    bool act = f < DO;
    int eh = lane >> 5;
    int beg = rowptr[row], cnt = deg[row];
    float acc = 0.f;
    int j = 0;
    for (; j + 7 < cnt; j += 8) {
        int s0 = csr_src[beg + j + 0 + eh], s1 = csr_src[beg + j + 2 + eh];
        int s2 = csr_src[beg + j + 4 + eh], s3 = csr_src[beg + j + 6 + eh];
        if (act) {
            float v0 = h3s[(long)s0 * DH + f], v1 = h3s[(long)s1 * DH + f];
            float v2 = h3s[(long)s2 * DH + f], v3 = h3s[(long)s3 * DH + f];
            acc += (v0 + v1) + (v2 + v3);
        }
    }
    for (; j < cnt; j += 2) {
        int jj = j + eh;
        if (act && jj < cnt) {
            int s = csr_src[beg + jj];
            acc += h3s[(long)s * DH + f];
        }
    }
    acc += __shfl_xor(acc, 32);
    if (lane < 32 && act) {
        float di = dinv[row];
        xo[(long)row * DO + f] = di * (acc + h3s[(long)row * DH + f]) + b2[f];
    }
}

// ---------------- softmax + argmax from xo ----------------
__global__ __launch_bounds__(256) void k_soft(const float* __restrict__ xo,
                                              float* __restrict__ logits,
                                              float* __restrict__ preds) {
    int wv = threadIdx.x >> 6, lane = threadIdx.x & 63;
    int row = blockIdx.x * 4 + wv;
    bool act = lane < DO;
    float val = act ? xo[(long)row * DO + lane] : -INFINITY;
    float m = val;
    for (int off = 32; off; off >>= 1) m = fmaxf(m, __shfl_xor(m, off));
    int idx = (act && val == m) ? lane : (1 << 30);
    for (int off = 32; off; off >>= 1) idx = min(idx, __shfl_xor(idx, off));
    float ev = act ? expf(val - m) : 0.f;
    float ssum = ev;
    for (int off = 32; off; off >>= 1) ssum += __shfl_xor(ssum, off);
    if (act) logits[(long)row * DO + lane] = ev / ssum;
    if (lane == 0) preds[row] = (float)idx;
}

extern "C" void kernel_launch(void* const* d_in, const int* in_sizes, int n_in,
                              void* d_out, int out_size, void* d_ws, size_t ws_size,
                              hipStream_t stream) {
    const float* x  = (const float*)d_in[0];
    const int*   ei = (const int*)d_in[1];
    const float* W1 = (const float*)d_in[2];
    const float* b1 = (const float*)d_in[3];
    const float* W2 = (const float*)d_in[4];
    const float* b2 = (const float*)d_in[5];
    const int* src = ei;          // edge_index[0]
    const int* dst = ei + NE;     // edge_index[1]

    float* out    = (float*)d_out;
    float* logits = out;                      // [N,47]
    float* preds  = out + (long)NN * DO;      // [N]
    float* xo     = preds + NN;               // [N,47]

    // workspace layout (~59 MB)
    char* wsb = (char*)d_ws;
    int*   deg     = (int*)wsb;                         wsb += (size_t)NN * 4;
    float* dinv    = (float*)wsb;                       wsb += (size_t)NN * 4;
    int*   rowptr  = (int*)wsb;                         wsb += (size_t)NN * 4;
    int*   cursor  = (int*)wsb;                         wsb += (size_t)NN * 4;
    int*   part    = (int*)wsb;                         wsb += (size_t)512 * 4;
    int*   csr_src = (int*)wsb;                         wsb += (size_t)NE * 4;
    float* h1s     = (float*)wsb;                       wsb += (size_t)NN * DH * 4;
    float* h2      = (float*)wsb;                       wsb += (size_t)NN * DH * 4;
    float* h3s     = h1s;   // alias: h1s is dead once agg1h passes complete

    hipMemsetAsync(deg, 0, NN * sizeof(int), stream);

    k_degree<<<(NE + 255) / 256, 256, 0, stream>>>(dst, deg);
    k_dinv<<<(NN + 255) / 256, 256, 0, stream>>>(deg, dinv);
    k_part<<<NB, 256, 0, stream>>>(deg, part);
    k_scanpart<<<1, 512, 0, stream>>>(part);
    k_scan3<<<NB, 256, 0, stream>>>(deg, part, rowptr, cursor);
    k_fillr<<<NRANGE * CPB, 256, 0, stream>>>(src, dst, cursor, csr_src);
    k_gemm1<<<(NN + 63) / 64, 512, 0, stream>>>(x, W1, dinv, h1s);
    k_agg1h<<<2 * HGRID, 256, 0, stream>>>(rowptr, deg, csr_src, dinv, h1s, b1, h2);
    k_gemm2<<<NN / 4, 256, 0, stream>>>(h2, W2, dinv, h3s);
    k_agg2h<<<2 * HGRID, 256, 0, stream>>>(rowptr, deg, csr_src, dinv, h3s, b2, xo);
    k_soft<<<NN / 4, 256, 0, stream>>>(xo, logits, preds);
}

// Round 7
// 427.887 us; speedup vs baseline: 1.2053x; 1.2053x over previous
//
#include <hip/hip_runtime.h>
#include <math.h>

#define NN 100000
#define NE 1600000
#define DI 256
#define DH 64
#define DO 47
#define DH3 48                      // h3s row stride: 192B -> 19.2 MB footprint
#define NB ((NN + 255) / 256)       // 391 scan blocks
#define NRANGE 4                    // dst ranges for locality-phased fill
#define RSZ ((NN + NRANGE - 1) / NRANGE)      // 25000 nodes per range
#define EPB 2048                    // edges per fill block
#define CPB ((NE + EPB - 1) / EPB)  // 782 chunks per range

typedef float f8 __attribute__((ext_vector_type(8)));

// ---------------- degree (int atomics, deterministic) ----------------
__global__ __launch_bounds__(256) void k_degree(const int* __restrict__ dst,
                                                int* __restrict__ deg) {
    int e = blockIdx.x * 256 + threadIdx.x;
    if (e < NE) atomicAdd(&deg[dst[e]], 1);
}

// ---------------- scan pass 1: per-block sums of deg ----------------
__global__ __launch_bounds__(256) void k_part(const int* __restrict__ deg,
                                              int* __restrict__ part) {
    int i = blockIdx.x * 256 + threadIdx.x;
    int v = (i < NN) ? deg[i] : 0;
    for (int off = 32; off; off >>= 1) v += __shfl_xor(v, off);
    __shared__ int s[4];
    if ((threadIdx.x & 63) == 0) s[threadIdx.x >> 6] = v;
    __syncthreads();
    if (threadIdx.x == 0) part[blockIdx.x] = s[0] + s[1] + s[2] + s[3];
}

// ---------------- scan pass 2: exclusive scan of partials (NB<=512) ----------------
__global__ __launch_bounds__(512) void k_scanpart(int* __restrict__ part) {
    int t = threadIdx.x, lane = t & 63, wv = t >> 6;
    int v0 = (t < NB) ? part[t] : 0;
    int v = v0;
    for (int off = 1; off < 64; off <<= 1) {
        int u = __shfl_up(v, off);
        if (lane >= off) v += u;
    }
    __shared__ int ws[8];
    if (lane == 63) ws[wv] = v;
    __syncthreads();
    if (t == 0) {
        int run = 0;
        for (int w = 0; w < 8; ++w) { int tmp = ws[w]; ws[w] = run; run += tmp; }
    }
    __syncthreads();
    v += ws[wv];
    if (t < NB) part[t] = v - v0;   // exclusive
}

// ---------------- scan pass 3: prefix -> rowptr, cursor; fused dinv ----------------
__global__ __launch_bounds__(256) void k_scan3(const int* __restrict__ deg,
                                               const int* __restrict__ part,
                                               int* __restrict__ rowptr,
                                               int* __restrict__ cursor,
                                               float* __restrict__ dinv) {
    int i = blockIdx.x * 256 + threadIdx.x;
    int lane = threadIdx.x & 63, wv = threadIdx.x >> 6;
    int v0 = (i < NN) ? deg[i] : 0;
    int v = v0;
    for (int off = 1; off < 64; off <<= 1) {
        int u = __shfl_up(v, off);
        if (lane >= off) v += u;
    }
    __shared__ int ws[4], wo[4];
    if (lane == 63) ws[wv] = v;
    __syncthreads();
    if (threadIdx.x == 0) {
        int run = 0;
        for (int w = 0; w < 4; ++w) { int tmp = ws[w]; wo[w] = run; run += tmp; }
    }
    __syncthreads();
    int excl = part[blockIdx.x] + wo[wv] + v - v0;
    if (i < NN) {
        rowptr[i] = excl;
        cursor[i] = excl;
        dinv[i] = rsqrtf((float)(v0 + 1));
    }
}

// ---------------- range-phased bucket-fill ----------------
// blockIdx = r*CPB + chunk, r major: co-resident blocks share one 25k-node dst
// range -> active csr_src write region ~1.6 MB, cache-resident -> no write amp.
__global__ __launch_bounds__(256) void k_fillr(const int* __restrict__ src,
                                               const int* __restrict__ dst,
                                               int* __restrict__ cursor,
                                               int* __restrict__ csr_src) {
    int r = blockIdx.x / CPB;
    int chunk = blockIdx.x % CPB;
    int lo = r * RSZ, hi = lo + RSZ;   // [lo, hi)
    int base = chunk * EPB + threadIdx.x;
    #pragma unroll
    for (int i = 0; i < EPB / 256; ++i) {
        int e = base + i * 256;
        if (e < NE) {
            int d = dst[e];
            if (d >= lo && d < hi) {
                int p = atomicAdd(&cursor[d], 1);
                csr_src[p] = src[e];
            }
        }
    }
}

// ---------------- h1s = dinv * (x @ W1)  (N x 256 x 64), fp32 ----------------
// 512 threads, 64 rows/block, lane = row; wave w owns cols [8w,8w+8).
// x double-buffered in LDS [64][17]; W1 slices are wave-uniform scalar loads.
__global__ __launch_bounds__(512) void k_gemm1(const float* __restrict__ x,
                                               const float* __restrict__ W1,
                                               const float* __restrict__ dinv,
                                               float* __restrict__ h1s) {
    __shared__ float xs[2][64 * 17];
    const int t = threadIdx.x;
    const int lane = t & 63;
    const int wvu = __builtin_amdgcn_readfirstlane(t >> 6);
    const int r0 = blockIdx.x * 64;
    const int sr = t >> 3;
    const int sk = (t & 7) * 2;
    const long xrow = (long)min(r0 + sr, NN - 1) * DI;
    const int row = r0 + lane;

    float acc[8] = {0.f, 0.f, 0.f, 0.f, 0.f, 0.f, 0.f, 0.f};

    {   // stage chunk 0
        float2 v = *(const float2*)(x + xrow + sk);
        xs[0][sr * 17 + sk] = v.x;
        xs[0][sr * 17 + sk + 1] = v.y;
    }
    __syncthreads();
    for (int c = 0; c < 16; ++c) {
        const int buf = c & 1;
        if (c + 1 < 16) {
            float2 v = *(const float2*)(x + xrow + (c + 1) * 16 + sk);
            xs[buf ^ 1][sr * 17 + sk] = v.x;
            xs[buf ^ 1][sr * 17 + sk + 1] = v.y;
        }
        const f8* wp = (const f8*)(W1) + (size_t)(c * 16) * (DH / 8) + wvu;
        #pragma unroll
        for (int k = 0; k < 16; ++k) {
            float xv = xs[buf][lane * 17 + k];
            f8 w8 = wp[(size_t)k * (DH / 8)];
            #pragma unroll
            for (int j = 0; j < 8; ++j) acc[j] += w8[j] * xv;
        }
        __syncthreads();
    }
    if (row < NN) {
        float di = dinv[row];
        float4 o0 = {di * acc[0], di * acc[1], di * acc[2], di * acc[3]};
        float4 o1 = {di * acc[4], di * acc[5], di * acc[6], di * acc[7]};
        float4* hp = (float4*)(h1s + (long)row * DH + wvu * 8);
        hp[0] = o0;
        hp[1] = o1;
    }
}

// ---------------- layer1 gather + relu/bias + GEMM2 fused ----------------
// agg = dinv[d]*(sum_s h1s[s] + h1s[d]); h2 = relu(agg+b1);
// h3s = dinv[d]*(h2 @ W2), row stride DH3=48.
__global__ __launch_bounds__(256) void k_agg1(const int* __restrict__ rowptr,
                                              const int* __restrict__ deg,
                                              const int* __restrict__ csr_src,
                                              const float* __restrict__ dinv,
                                              const float* __restrict__ h1s,
                                              const float* __restrict__ b1,
                                              const float* __restrict__ W2,
                                              float* __restrict__ h3s) {
    __shared__ float w2[DH * DO];   // 12 KB
    __shared__ float sh[4][DH];
    for (int i = threadIdx.x; i < DH * DO; i += 256) w2[i] = W2[i];
    __syncthreads();
    int wv = threadIdx.x >> 6, lane = threadIdx.x & 63;
    int row = blockIdx.x * 4 + wv;   // NN % 4 == 0
    int beg = rowptr[row], cnt = deg[row];
    float acc = 0.f;
    int j = 0;
    for (; j + 7 < cnt; j += 8) {
        int s0 = csr_src[beg + j + 0], s1 = csr_src[beg + j + 1];
        int s2 = csr_src[beg + j + 2], s3 = csr_src[beg + j + 3];
        int s4 = csr_src[beg + j + 4], s5 = csr_src[beg + j + 5];
        int s6 = csr_src[beg + j + 6], s7 = csr_src[beg + j + 7];
        float v0 = h1s[(long)s0 * DH + lane], v1 = h1s[(long)s1 * DH + lane];
        float v2 = h1s[(long)s2 * DH + lane], v3 = h1s[(long)s3 * DH + lane];
        float v4 = h1s[(long)s4 * DH + lane], v5 = h1s[(long)s5 * DH + lane];
        float v6 = h1s[(long)s6 * DH + lane], v7 = h1s[(long)s7 * DH + lane];
        acc += ((v0 + v1) + (v2 + v3)) + ((v4 + v5) + (v6 + v7));
    }
    for (; j < cnt; ++j) {
        int s = csr_src[beg + j];
        acc += h1s[(long)s * DH + lane];
    }
    float di = dinv[row];
    float v = di * (acc + h1s[(long)row * DH + lane]) + b1[lane];
    sh[wv][lane] = fmaxf(v, 0.f);
    __syncthreads();
    if (lane < DO) {
        float o = 0.f;
        #pragma unroll 8
        for (int k = 0; k < DH; ++k)
            o += sh[wv][k] * w2[k * DO + lane];
        h3s[(long)row * DH3 + lane] = di * o;
    }
}

// ---------------- layer2 gather + self-loop/bias + softmax/argmax fused ----------------
__global__ __launch_bounds__(256) void k_agg2(const int* __restrict__ rowptr,
                                              const int* __restrict__ deg,
                                              const int* __restrict__ csr_src,
                                              const float* __restrict__ dinv,
                                              const float* __restrict__ h3s,
                                              const float* __restrict__ b2,
                                              float* __restrict__ logits,
                                              float* __restrict__ preds,
                                              float* __restrict__ xo) {
    int wv = threadIdx.x >> 6, lane = threadIdx.x & 63;
    int row = blockIdx.x * 4 + wv;
    int beg = rowptr[row], cnt = deg[row];
    float acc = 0.f;
    bool act = lane < DO;
    int lx = act ? lane : 0;   // inactive lanes load col 0 (no OOB, uniform issue)
    int j = 0;
    for (; j + 7 < cnt; j += 8) {
        int s0 = csr_src[beg + j + 0], s1 = csr_src[beg + j + 1];
        int s2 = csr_src[beg + j + 2], s3 = csr_src[beg + j + 3];
        int s4 = csr_src[beg + j + 4], s5 = csr_src[beg + j + 5];
        int s6 = csr_src[beg + j + 6], s7 = csr_src[beg + j + 7];
        float v0 = h3s[(long)s0 * DH3 + lx], v1 = h3s[(long)s1 * DH3 + lx];
        float v2 = h3s[(long)s2 * DH3 + lx], v3 = h3s[(long)s3 * DH3 + lx];
        float v4 = h3s[(long)s4 * DH3 + lx], v5 = h3s[(long)s5 * DH3 + lx];
        float v6 = h3s[(long)s6 * DH3 + lx], v7 = h3s[(long)s7 * DH3 + lx];
        acc += ((v0 + v1) + (v2 + v3)) + ((v4 + v5) + (v6 + v7));
    }
    for (; j < cnt; ++j) {
        int s = csr_src[beg + j];
        acc += h3s[(long)s * DH3 + lx];
    }
    float di = dinv[row];
    float val = -INFINITY;
    if (act) {
        val = di * (acc + h3s[(long)row * DH3 + lane]) + b2[lane];
        xo[(long)row * DO + lane] = val;
    }
    float m = val;
    for (int off = 32; off; off >>= 1) m = fmaxf(m, __shfl_xor(m, off));
    int idx = (act && val == m) ? lane : (1 << 30);
    for (int off = 32; off; off >>= 1) idx = min(idx, __shfl_xor(idx, off));
    float ev = act ? expf(val - m) : 0.f;
    float ssum = ev;
    for (int off = 32; off; off >>= 1) ssum += __shfl_xor(ssum, off);
    if (act) logits[(long)row * DO + lane] = ev / ssum;
    if (lane == 0) preds[row] = (float)idx;
}

extern "C" void kernel_launch(void* const* d_in, const int* in_sizes, int n_in,
                              void* d_out, int out_size, void* d_ws, size_t ws_size,
                              hipStream_t stream) {
    const float* x  = (const float*)d_in[0];
    const int*   ei = (const int*)d_in[1];
    const float* W1 = (const float*)d_in[2];
    const float* b1 = (const float*)d_in[3];
    const float* W2 = (const float*)d_in[4];
    const float* b2 = (const float*)d_in[5];
    const int* src = ei;          // edge_index[0]
    const int* dst = ei + NE;     // edge_index[1]

    float* out    = (float*)d_out;
    float* logits = out;                      // [N,47]
    float* preds  = out + (long)NN * DO;      // [N]
    float* xo     = preds + NN;               // [N,47]

    // workspace layout (~53 MB)
    char* wsb = (char*)d_ws;
    int*   deg     = (int*)wsb;                         wsb += (size_t)NN * 4;
    float* dinv    = (float*)wsb;                       wsb += (size_t)NN * 4;
    int*   rowptr  = (int*)wsb;                         wsb += (size_t)NN * 4;
    int*   cursor  = (int*)wsb;                         wsb += (size_t)NN * 4;
    int*   part    = (int*)wsb;                         wsb += (size_t)512 * 4;
    int*   csr_src = (int*)wsb;                         wsb += (size_t)NE * 4;
    float* h1s     = (float*)wsb;                       wsb += (size_t)NN * DH * 4;
    float* h3s     = (float*)wsb;                       wsb += (size_t)NN * DH3 * 4;

    hipMemsetAsync(deg, 0, NN * sizeof(int), stream);

    k_degree<<<(NE + 255) / 256, 256, 0, stream>>>(dst, deg);
    k_part<<<NB, 256, 0, stream>>>(deg, part);
    k_scanpart<<<1, 512, 0, stream>>>(part);
    k_scan3<<<NB, 256, 0, stream>>>(deg, part, rowptr, cursor, dinv);
    k_fillr<<<NRANGE * CPB, 256, 0, stream>>>(src, dst, cursor, csr_src);
    k_gemm1<<<(NN + 63) / 64, 512, 0, stream>>>(x, W1, dinv, h1s);
    k_agg1<<<NN / 4, 256, 0, stream>>>(rowptr, deg, csr_src, dinv, h1s, b1, W2, h3s);
    k_agg2<<<NN / 4, 256, 0, stream>>>(rowptr, deg, csr_src, dinv, h3s, b2, logits, preds, xo);
}